// Round 9
// baseline (170.531 us; speedup 1.0000x reference)
//
#include <hip/hip_runtime.h>
#include <hip/hip_bf16.h>

// CausalMixer: B=128, T=64, NA=10, NV=16, K=4, SD=512, H=256, E=32. 8192 rows.
// Round 9: ks-outer / strips-inner K-loop. Per wave: 7 phase-A strips (5 in
// phase B) with all accumulators live; per ks, ONE LDS A-read pair feeds all
// strips and 7 independent B-loads queue in parallel. Prep/fallback from R8.

typedef __hip_bfloat16 bf16;
typedef unsigned short ushort_t;
typedef __attribute__((ext_vector_type(8))) short short8;
typedef __attribute__((ext_vector_type(4))) float f32x4;

#define PA_OFF 0
#define PA_TILES 56                                  // N=896 padded (844 real)
#define PB_OFF (PA_TILES * 16 * 64 * 8 * 2)          // 917504
#define PB_TILES 36                                  // N=576 exact
#define FB_OFF (PB_OFF + PB_TILES * 8 * 64 * 8 * 2)  // 1212416
#define NCST 2854
#define WS_NEED (size_t)(FB_OFF + NCST * 4 + 32)

#define MFMA16(a, b, c) __builtin_amdgcn_mfma_f32_16x16x32_bf16(a, b, c, 0, 0, 0)

__device__ __forceinline__ float us2f(ushort_t x) {
  unsigned u = ((unsigned)x) << 16; float f; __builtin_memcpy(&f, &u, 4); return f;
}
__device__ __forceinline__ ushort_t f2us(float v) {
  bf16 h = __float2bfloat16(v); ushort_t r; __builtin_memcpy(&r, &h, 2); return r;
}
template <bool F32>
__device__ __forceinline__ float LD(const void* p, size_t i) {
  if (F32) return ((const float*)p)[i];
  return us2f(((const ushort_t*)p)[i]);
}

// wave-level dtype probe: 1 = float32, 0 = bf16
__device__ __forceinline__ int detect_f32(const void* states) {
  const unsigned short* u = (const unsigned short*)states;
  int lane = threadIdx.x & 63;
  int bad = 0;
  for (int i = lane; i < 512; i += 64) {
    unsigned short x = u[i];
    int e = (x >> 7) & 0xFF;
    if (e > 140 || (((x & 0x7FFFu) != 0) && e < 100)) bad++;
  }
  for (int off = 32; off; off >>= 1) bad += __shfl_down(bad, off);
  return __shfl(bad, 0) > 20;
}

// packed-layout stores: element (n', k) -> MFMA lane order
__device__ __forceinline__ void pa_store(ushort_t* pa, int np, int k, ushort_t v) {
  int t = np >> 4, lm = np & 15, ks = k >> 5, qq = (k >> 3) & 3, j = k & 7;
  pa[(size_t)t * 8192 + ks * 512 + (qq * 16 + lm) * 8 + j] = v;
}
__device__ __forceinline__ void pb_store(ushort_t* pb, int np, int k, ushort_t v) {
  int t = np >> 4, lm = np & 15, ks = k >> 5, qq = (k >> 3) & 3, j = k & 7;
  pb[(size_t)t * 4096 + ks * 512 + (qq * 16 + lm) * 8 + j] = v;
}

// ---------------- prep: source-major coalesced reads, scattered u16 writes ----
template <bool F32>
__device__ void prep_body(int gtid, int T, char* ws,
    const void* w00l1W, const void* w00l1b, const void* w00l2W, const void* w00l2b,
    const void* b00W, const void* b00b,
    const void* w01W, const void* w01b, const void* b01W, const void* b01b,
    const void* w1l1W, const void* w1l1b, const void* w1l2W, const void* w1l2b,
    const void* b1W, const void* b1b,
    const void* w2l1W, const void* w2l1b, const void* w2l2W, const void* w2l2b,
    const void* b2l1W, const void* b2l1b, const void* b2l2W, const void* b2l2b) {
  ushort_t* pa = (ushort_t*)(ws + PA_OFF);
  ushort_t* pb = (ushort_t*)(ws + PB_OFF);
  float* cst = (float*)(ws + FB_OFF);
  for (int i = gtid; i < 131072; i += T) {
    int k = i >> 8, n = i & 255;
    pa_store(pa, n, k, f2us(LD<F32>(w1l1W, i)));
    pa_store(pa, 256 + n, k, f2us(LD<F32>(w2l1W, i)));
    pa_store(pa, 512 + n, k, f2us(LD<F32>(w00l1W, i)));
  }
  for (int i = gtid; i < 16384; i += T) {
    int k = i >> 5, n = i & 31;
    pa_store(pa, 768 + n, k, f2us(LD<F32>(b1W, i)));
    pa_store(pa, 800 + n, k, f2us(LD<F32>(b2l1W, i)));
  }
  for (int i = gtid; i < 5120; i += T) {
    int k = i / 10, n = i % 10;
    pa_store(pa, 832 + n, k, f2us(LD<F32>(w01W, i)));
  }
  for (int i = gtid; i < 512; i += T) {
    pa_store(pa, 842, i, f2us(LD<F32>(b00W, i)));
    pa_store(pa, 843, i, f2us(LD<F32>(b01W, i)));
  }
  // zero garbage lanes of tile 52 (n' 844..847)
  for (int z = gtid; z < 2048; z += T) {
    int ks = z >> 7, qq = (z >> 5) & 3, lm = 12 + ((z >> 3) & 3), j = z & 7;
    pa[(size_t)52 * 8192 + ks * 512 + (qq * 16 + lm) * 8 + j] = 0;
  }
  for (int i = gtid; i < 139264; i += T) {
    int k = i / 544, n = i % 544;
    pb_store(pb, n, k, f2us(LD<F32>(w1l2W, i)));
  }
  for (int i = gtid; i < 8192; i += T) {
    int k = i >> 5, n = i & 31;
    pb_store(pb, 544 + n, k, f2us(LD<F32>(w2l2W, i)));
  }
  // consts: biasA[0,896) biasB[896,1536) hd[1536,1792) w00l2W[1792,2816)
  //         w00l2b[2816,2820) b2l2W[2820,2852) b2l2b[2852] gd[2853]
  for (int i = gtid; i < NCST; i += T) {
    float x;
    if (i < 896) {
      int c = i;
      if (c < 256) x = LD<F32>(w1l1b, c);
      else if (c < 512) x = LD<F32>(w2l1b, c - 256);
      else if (c < 768) x = LD<F32>(w00l1b, c - 512);
      else if (c < 800) x = LD<F32>(b1b, c - 768);
      else if (c < 832) x = LD<F32>(b2l1b, c - 800);
      else if (c < 842) x = LD<F32>(w01b, c - 832);
      else if (c == 842) x = LD<F32>(b00b, 0);
      else if (c == 843) x = LD<F32>(b01b, 0);
      else x = 0.f;
    } else if (i < 1536) {
      int c = i - 896;
      x = (c < 544) ? LD<F32>(w1l2b, c) : (c < 576 ? LD<F32>(w2l2b, c - 544) : 0.f);
    } else if (i < 1792) {
      int j = i - 1536; float s = 0.f;
      for (int z = 0; z < 16; ++z) s += LD<F32>(w00l1W, (size_t)(512 + z) * 256 + j);
      x = s;
    } else if (i < 2816) x = LD<F32>(w00l2W, i - 1792);
    else if (i < 2820) x = LD<F32>(w00l2b, i - 2816);
    else if (i < 2852) x = LD<F32>(b2l2W, i - 2820);
    else if (i == 2852) x = LD<F32>(b2l2b, 0);
    else { float s = 0.f; for (int z = 0; z < 16; ++z) s += LD<F32>(b00W, 512 + z); x = s; }
    cst[i] = x;
  }
}

__global__ __launch_bounds__(256) void prep_kernel(char* ws, const void* states,
    const void* w00l1W, const void* w00l1b, const void* w00l2W, const void* w00l2b,
    const void* b00W, const void* b00b,
    const void* w01W, const void* w01b, const void* b01W, const void* b01b,
    const void* w1l1W, const void* w1l1b, const void* w1l2W, const void* w1l2b,
    const void* b1W, const void* b1b,
    const void* w2l1W, const void* w2l1b, const void* w2l2W, const void* w2l2b,
    const void* b2l1W, const void* b2l1b, const void* b2l2W, const void* b2l2b) {
  int gtid = blockIdx.x * 256 + threadIdx.x;
  int T = gridDim.x * 256;
  if (detect_f32(states))
    prep_body<true>(gtid, T, ws, w00l1W, w00l1b, w00l2W, w00l2b, b00W, b00b,
        w01W, w01b, b01W, b01b, w1l1W, w1l1b, w1l2W, w1l2b, b1W, b1b,
        w2l1W, w2l1b, w2l2W, w2l2b, b2l1W, b2l1b, b2l2W, b2l2b);
  else
    prep_body<false>(gtid, T, ws, w00l1W, w00l1b, w00l2W, w00l2b, b00W, b00b,
        w01W, w01b, b01W, b01b, w1l1W, w1l1b, w1l2W, w1l2b, b1W, b1b,
        w2l1W, w2l1b, w2l2W, w2l2b, b2l1W, b2l1b, b2l2W, b2l2b);
}

// ---------------- main MFMA kernel: 32 rows/block, 8 waves ----------------
struct SmemM {
  union {
    __align__(16) ushort_t sA[2][8192];   // states, MFMA lane order (phase A only)
    __align__(16) ushort_t w1a[32][544];  // |w1 raw| bf16 (phase B output)
  } u;
  __align__(16) ushort_t Am1[2][4096];    // relu(s@w1l1+b), lane order
  __align__(16) ushort_t Am2[2][4096];    // relu(s@w2l1+b), lane order
  __align__(16) ushort_t hb[32][264];     // s@w00l1+b (pre-relu), linear
  float hd[256];
  float b1v[32][32];
  float rbv[32][32];
  float w2v[32][32];
  float w01v[32][12];
  float qv[32][10];
  unsigned char cr[32][64];
  float w0c[32][4], w0s[32][4];
  float gq[32][18];
  float gbv[32], b01v[32];
  float hid[32][33];
};

template <bool F32>
__device__ void mixer_body(SmemM& sm, const char* ws, int n0,
    const void* qvals, const int* crel, const void* states, void* out) {
  const int tid = threadIdx.x;                // 0..511
  const int lane = tid & 63, wv = tid >> 6;   // 8 waves
  const int q = lane >> 4, lm = lane & 15;
  const int b_blk = n0 >> 6;
  const ushort_t* pa = (const ushort_t*)(ws + PA_OFF);
  const ushort_t* pb = (const ushort_t*)(ws + PB_OFF);
  const float* cstg = (const float*)(ws + FB_OFF);

  // ---- stage: states -> sA in MFMA lane order; qv/cr; hd ----
  for (int fi = tid; fi < 2048; fi += 512) {
    int ln = fi & 63, ks = (fi >> 6) & 15, G = fi >> 10;
    int row = G * 16 + (ln & 15), col = ks * 32 + (ln >> 4) * 8;
    if (F32) {
      const f32x4* p = (const f32x4*)((const float*)states + (size_t)(n0 + row) * 512 + col);
      f32x4 v0 = p[0], v1 = p[1];
      ushort_t v[8];
      v[0] = f2us(v0[0]); v[1] = f2us(v0[1]); v[2] = f2us(v0[2]); v[3] = f2us(v0[3]);
      v[4] = f2us(v1[0]); v[5] = f2us(v1[1]); v[6] = f2us(v1[2]); v[7] = f2us(v1[3]);
      *(short8*)&sm.u.sA[G][(size_t)(ks * 64 + ln) * 8] = *(short8*)v;
    } else {
      *(short8*)&sm.u.sA[G][(size_t)(ks * 64 + ln) * 8] =
          *(const short8*)((const ushort_t*)states + (size_t)(n0 + row) * 512 + col);
    }
  }
  for (int i = tid; i < 320; i += 512) sm.qv[i / 10][i % 10] = LD<F32>(qvals, (size_t)(n0 + i / 10) * 10 + i % 10);
  for (int i = tid; i < 2048; i += 512) sm.cr[i >> 6][i & 63] = (unsigned char)crel[(size_t)n0 * 64 + i];
  if (tid < 256) sm.hd[tid] = cstg[1536 + tid];
  __syncthreads();

  // ---- Phase A: ks-outer, 7 strips/wave inner. acc live across K. ----
  {
    int sidx[7]; bool sreal[7];
#pragma unroll
    for (int i = 0; i < 7; ++i) {
      int s = wv + 8 * i;
      sreal[i] = (s < 53);
      sidx[i] = sreal[i] ? s : wv;   // dummy slots re-read tile wv (discarded)
    }
    f32x4 accA[7][2];
#pragma unroll
    for (int i = 0; i < 7; ++i) { accA[i][0] = (f32x4){0,0,0,0}; accA[i][1] = (f32x4){0,0,0,0}; }
    const ushort_t* base = pa + lane * 8;
    short8 cur[7], nxt[7];
#pragma unroll
    for (int i = 0; i < 7; ++i) cur[i] = *(const short8*)(base + (size_t)sidx[i] * 8192);
#pragma unroll
    for (int ks = 0; ks < 16; ++ks) {
      if (ks < 15) {
#pragma unroll
        for (int i = 0; i < 7; ++i)
          nxt[i] = *(const short8*)(base + (size_t)sidx[i] * 8192 + (ks + 1) * 512);
      }
      short8 a0 = *(const short8*)&sm.u.sA[0][(ks * 64 + lane) * 8];
      short8 a1 = *(const short8*)&sm.u.sA[1][(ks * 64 + lane) * 8];
#pragma unroll
      for (int i = 0; i < 7; ++i) {
        accA[i][0] = MFMA16(a0, cur[i], accA[i][0]);
        accA[i][1] = MFMA16(a1, cur[i], accA[i][1]);
      }
#pragma unroll
      for (int i = 0; i < 7; ++i) cur[i] = nxt[i];
    }
    // writeback
#pragma unroll
    for (int i = 0; i < 7; ++i) {
      if (!sreal[i]) continue;
      int c = sidx[i] * 16 + lm;
      if (c >= 844) continue;
      float bias = cstg[c];
      int ks2 = (c & 255) >> 5, q2 = (c >> 3) & 3, j2 = c & 7;
#pragma unroll
      for (int G = 0; G < 2; ++G) {
        f32x4 acc = accA[i][G];
        int rb = G * 16 + q * 4;
        if (c < 256) {
#pragma unroll
          for (int g = 0; g < 4; ++g) {
            float v = acc[g] + bias;
            sm.Am1[G][(ks2 * 64 + q2 * 16 + q * 4 + g) * 8 + j2] = f2us(v > 0.f ? v : 0.f);
          }
        } else if (c < 512) {
#pragma unroll
          for (int g = 0; g < 4; ++g) {
            float v = acc[g] + bias;
            sm.Am2[G][(ks2 * 64 + q2 * 16 + q * 4 + g) * 8 + j2] = f2us(v > 0.f ? v : 0.f);
          }
        } else if (c < 768) {
#pragma unroll
          for (int g = 0; g < 4; ++g) sm.hb[rb + g][c - 512] = f2us(acc[g] + bias);
        } else if (c < 800) {
#pragma unroll
          for (int g = 0; g < 4; ++g) sm.b1v[rb + g][c - 768] = acc[g] + bias;
        } else if (c < 832) {
#pragma unroll
          for (int g = 0; g < 4; ++g) { float v = acc[g] + bias; sm.rbv[rb + g][c - 800] = v > 0.f ? v : 0.f; }
        } else if (c < 842) {
#pragma unroll
          for (int g = 0; g < 4; ++g) sm.w01v[rb + g][c - 832] = acc[g] + bias;
        } else if (c == 842) {
#pragma unroll
          for (int g = 0; g < 4; ++g) sm.gbv[rb + g] = acc[g] + bias;
        } else {
#pragma unroll
          for (int g = 0; g < 4; ++g) sm.b01v[rb + g] = acc[g] + bias;
        }
      }
    }
  }
  __syncthreads();

  // ---- Phase B: ks-outer, 5 strips/wave. strips 0..33 from Am1, 34..35 Am2 ----
  {
    int tix[5]; bool treal[5];
#pragma unroll
    for (int i = 0; i < 5; ++i) {
      int t = wv + 8 * i;
      treal[i] = (t < 36);
      tix[i] = treal[i] ? t : wv;
    }
    f32x4 accB[5][2];
#pragma unroll
    for (int i = 0; i < 5; ++i) { accB[i][0] = (f32x4){0,0,0,0}; accB[i][1] = (f32x4){0,0,0,0}; }
    const ushort_t* base = pb + lane * 8;
    short8 cur[5], nxt[5];
#pragma unroll
    for (int i = 0; i < 5; ++i) cur[i] = *(const short8*)(base + (size_t)tix[i] * 4096);
#pragma unroll
    for (int ks = 0; ks < 8; ++ks) {
      if (ks < 7) {
#pragma unroll
        for (int i = 0; i < 5; ++i)
          nxt[i] = *(const short8*)(base + (size_t)tix[i] * 4096 + (ks + 1) * 512);
      }
      short8 m1a0 = *(const short8*)&sm.Am1[0][(ks * 64 + lane) * 8];
      short8 m1a1 = *(const short8*)&sm.Am1[1][(ks * 64 + lane) * 8];
      short8 m2a0 = *(const short8*)&sm.Am2[0][(ks * 64 + lane) * 8];
      short8 m2a1 = *(const short8*)&sm.Am2[1][(ks * 64 + lane) * 8];
#pragma unroll
      for (int i = 0; i < 5; ++i) {
        short8 x0 = (tix[i] < 34) ? m1a0 : m2a0;
        short8 x1 = (tix[i] < 34) ? m1a1 : m2a1;
        accB[i][0] = MFMA16(x0, cur[i], accB[i][0]);
        accB[i][1] = MFMA16(x1, cur[i], accB[i][1]);
      }
#pragma unroll
      for (int i = 0; i < 5; ++i) cur[i] = nxt[i];
    }
#pragma unroll
    for (int i = 0; i < 5; ++i) {
      if (!treal[i]) continue;
      int c = tix[i] * 16 + lm;
      float bias = cstg[896 + c];
#pragma unroll
      for (int G = 0; G < 2; ++G) {
        f32x4 acc = accB[i][G];
        int rb = G * 16 + q * 4;
        if (c < 544) {
#pragma unroll
          for (int g = 0; g < 4; ++g) sm.u.w1a[rb + g][c] = f2us(fabsf(acc[g] + bias));
        } else {
          int e = c - 544;
#pragma unroll
          for (int g = 0; g < 4; ++g) sm.w2v[rb + g][e] = fabsf(acc[g] + bias);
        }
      }
    }
  }
  __syncthreads();

  // ---- C1: w0c/w0s = relu(hb [+hd]) @ w00l2 + b ----
  if (tid < 256) {
    int r = tid >> 3, k = (tid >> 1) & 3, sflag = tid & 1;
    const float* wl = cstg + 1792;
    float a = 0.f;
    for (int j = 0; j < 256; ++j) {
      float h = us2f(sm.hb[r][j]);
      if (sflag) h += sm.hd[j];
      h = h > 0.f ? h : 0.f;
      a = fmaf(h, wl[j * 4 + k], a);
    }
    a += cstg[2816 + k];
    if (sflag) sm.w0s[r][k] = a; else sm.w0c[r][k] = a;
  }
  __syncthreads();

  // ---- C2: gq ----
  {
    int r = tid >> 4, v = tid & 15;
    bool sp = (v == b_blk);
    const float* w0 = sp ? sm.w0s[r] : sm.w0c[r];
    float g = sm.gbv[r] + (sp ? cstg[2853] : 0.f);
#pragma unroll
    for (int k = 0; k < 4; ++k) {
      int a = sm.cr[r][k * 16 + v];
      g = fmaf(sm.qv[r][a], fabsf(w0[k]), g);
    }
    sm.gq[r][v] = g;
  }
  if (tid < 32) {
    float o = sm.b01v[tid];
#pragma unroll
    for (int a = 0; a < 10; ++a) o = fmaf(sm.qv[tid][a], sm.w01v[tid][a], o);
    sm.gq[tid][16] = o;
  }
  __syncthreads();

  // ---- C3: hidden = elu(sum_v gq*|w1| + b1); fuse *w2 + rb*b2l2W ----
  for (int p = tid; p < 1024; p += 512) {
    int r = p >> 5, e = p & 31;
    float h = sm.b1v[r][e];
#pragma unroll
    for (int v = 0; v < 17; ++v) h = fmaf(sm.gq[r][v], us2f(sm.u.w1a[r][v * 32 + e]), h);
    float hid = h > 0.f ? h : (expf(h) - 1.f);
    sm.hid[r][e] = hid * sm.w2v[r][e] + sm.rbv[r][e] * cstg[2820 + e];
  }
  __syncthreads();

  // ---- C4: reduce + store ----
  if (tid < 32) {
    float y = cstg[2852];
#pragma unroll
    for (int e = 0; e < 32; ++e) y += sm.hid[tid][e];
    if (F32) ((float*)out)[n0 + tid] = y;
    else ((bf16*)out)[n0 + tid] = __float2bfloat16(y);
  }
}

__global__ __launch_bounds__(512, 2) void causal_mixer_mfma(const char* ws,
    const void* qvals, const int* crel, const void* states, void* out) {
  __shared__ SmemM sm;
  int n0 = blockIdx.x * 32;
  if (detect_f32(states))
    mixer_body<true>(sm, ws, n0, qvals, crel, states, out);
  else
    mixer_body<false>(sm, ws, n0, qvals, crel, states, out);
}

// ---------------- fallback scalar kernel (round-2, proven) ----------------
struct SmemF {
  float s[16][516]; float buf[16][258]; float hd[256];
  float q[16][10]; int cr[16][66];
  float w0c[16][4], w0s[16][4]; float gq[16][17];
  float w01[16][10]; float b01[16]; float gb[16]; float gd;
  float hid[16][32]; float w2[16][32]; float rb[16][32];
};

template <bool F32>
__device__ void fb_body(SmemF& sm, int tid, int n0, int b_blk,
    const void* qvals, const int* crel, const void* states,
    const void* w00l1W, const void* w00l1b, const void* w00l2W, const void* w00l2b,
    const void* b00W, const void* b00b,
    const void* w01W, const void* w01b, const void* b01W, const void* b01b,
    const void* w1l1W, const void* w1l1b, const void* w1l2W, const void* w1l2b,
    const void* b1W, const void* b1b,
    const void* w2l1W, const void* w2l1b, const void* w2l2W, const void* w2l2b,
    const void* b2l1W, const void* b2l1b, const void* b2l2W, const void* b2l2b,
    void* out) {
  for (int idx = tid; idx < 16 * 512; idx += 256) {
    int r = idx >> 9, i = idx & 511;
    sm.s[r][i] = LD<F32>(states, (size_t)(n0 + r) * 512 + i);
  }
  for (int idx = tid; idx < 160; idx += 256) {
    int r = idx / 10, a = idx % 10;
    sm.q[r][a] = LD<F32>(qvals, (size_t)(n0 + r) * 10 + a);
  }
  for (int idx = tid; idx < 16 * 64; idx += 256) {
    int r = idx >> 6, kv = idx & 63;
    sm.cr[r][kv] = crel[(size_t)(n0 + r) * 64 + kv];
  }
  if (tid == 0) {
    float gd = 0.f;
    for (int i = 512; i < 528; ++i) gd += LD<F32>(b00W, i);
    sm.gd = gd;
  }
  __syncthreads();
  {
    const int j = tid;
    float hd = 0.f;
    for (int i = 0; i < 16; ++i) hd += LD<F32>(w00l1W, (size_t)(512 + i) * 256 + j);
    sm.hd[j] = hd;
    float acc[16]; float bj = LD<F32>(w00l1b, j);
#pragma unroll
    for (int r = 0; r < 16; ++r) acc[r] = bj;
    for (int i = 0; i < 512; ++i) {
      float w = LD<F32>(w00l1W, (size_t)i * 256 + j);
#pragma unroll
      for (int r = 0; r < 16; ++r) acc[r] = fmaf(sm.s[r][i], w, acc[r]);
    }
#pragma unroll
    for (int r = 0; r < 16; ++r) sm.buf[r][j] = acc[r];
  }
  __syncthreads();
  if (tid < 64) {
    int r = tid >> 2, k = tid & 3;
    float aC = 0.f, aS = 0.f;
    for (int j = 0; j < 256; ++j) {
      float hb = sm.buf[r][j];
      float w = LD<F32>(w00l2W, j * 4 + k);
      float hc = hb > 0.f ? hb : 0.f;
      float hbs = hb + sm.hd[j];
      float hsv = hbs > 0.f ? hbs : 0.f;
      aC = fmaf(hc, w, aC); aS = fmaf(hsv, w, aS);
    }
    float bk = LD<F32>(w00l2b, k);
    sm.w0c[r][k] = aC + bk; sm.w0s[r][k] = aS + bk;
  } else if (tid < 224) {
    int p = tid - 64; int r = p / 10, a = p % 10;
    float acc = 0.f;
    for (int i = 0; i < 512; ++i) acc = fmaf(sm.s[r][i], LD<F32>(w01W, (size_t)i * 10 + a), acc);
    sm.w01[r][a] = acc + LD<F32>(w01b, a);
  } else if (tid < 240) {
    int r = tid - 224;
    float acc = 0.f;
    for (int i = 0; i < 512; ++i) acc = fmaf(sm.s[r][i], LD<F32>(b00W, i), acc);
    sm.gb[r] = acc + LD<F32>(b00b, 0);
  } else {
    int r = tid - 240;
    float acc = 0.f;
    for (int i = 0; i < 512; ++i) acc = fmaf(sm.s[r][i], LD<F32>(b01W, i), acc);
    sm.b01[r] = acc + LD<F32>(b01b, 0);
  }
  __syncthreads();
  {
    int r = tid >> 4, v = tid & 15;
    bool sp = (v == b_blk);
    const float* w0 = sp ? sm.w0s[r] : sm.w0c[r];
    float g = sm.gb[r] + (sp ? sm.gd : 0.f);
#pragma unroll
    for (int k = 0; k < 4; ++k) {
      int a = sm.cr[r][k * 16 + v];
      g = fmaf(sm.q[r][a], fabsf(w0[k]), g);
    }
    sm.gq[r][v] = g;
  }
  if (tid < 16) {
    int r = tid;
    float o = sm.b01[r];
    for (int a = 0; a < 10; ++a) o = fmaf(sm.q[r][a], sm.w01[r][a], o);
    sm.gq[r][16] = o;
  }
  __syncthreads();
  {
    const int j = tid;
    float acc[16]; float bj = LD<F32>(w1l1b, j);
#pragma unroll
    for (int r = 0; r < 16; ++r) acc[r] = bj;
    for (int i = 0; i < 512; ++i) {
      float w = LD<F32>(w1l1W, (size_t)i * 256 + j);
#pragma unroll
      for (int r = 0; r < 16; ++r) acc[r] = fmaf(sm.s[r][i], w, acc[r]);
    }
#pragma unroll
    for (int r = 0; r < 16; ++r) sm.buf[r][j] = acc[r] > 0.f ? acc[r] : 0.f;
  }
  __syncthreads();
  for (int p = tid; p < 512; p += 256) {
    int r = p >> 5, e = p & 31;
    float acc = 0.f;
    for (int v = 0; v < 17; ++v) {
      int c = v * 32 + e;
      float d = LD<F32>(w1l2b, c);
      for (int j = 0; j < 256; ++j) d = fmaf(sm.buf[r][j], LD<F32>(w1l2W, (size_t)j * 544 + c), d);
      acc = fmaf(sm.gq[r][v], fabsf(d), acc);
    }
    float b1v = LD<F32>(b1b, e);
    for (int i = 0; i < 512; ++i) b1v = fmaf(sm.s[r][i], LD<F32>(b1W, (size_t)i * 32 + e), b1v);
    float x = acc + b1v;
    sm.hid[r][e] = x > 0.f ? x : (expf(x) - 1.f);
  }
  __syncthreads();
  {
    const int j = tid;
    float acc[16]; float bj = LD<F32>(w2l1b, j);
#pragma unroll
    for (int r = 0; r < 16; ++r) acc[r] = bj;
    for (int i = 0; i < 512; ++i) {
      float w = LD<F32>(w2l1W, (size_t)i * 256 + j);
#pragma unroll
      for (int r = 0; r < 16; ++r) acc[r] = fmaf(sm.s[r][i], w, acc[r]);
    }
#pragma unroll
    for (int r = 0; r < 16; ++r) sm.buf[r][j] = acc[r] > 0.f ? acc[r] : 0.f;
  }
  __syncthreads();
  for (int p = tid; p < 512; p += 256) {
    int r = p >> 5, e = p & 31;
    float d = LD<F32>(w2l2b, e);
    for (int j = 0; j < 256; ++j) d = fmaf(sm.buf[r][j], LD<F32>(w2l2W, (size_t)j * 32 + e), d);
    sm.w2[r][e] = fabsf(d);
    float rb = LD<F32>(b2l1b, e);
    for (int i = 0; i < 512; ++i) rb = fmaf(sm.s[r][i], LD<F32>(b2l1W, (size_t)i * 32 + e), rb);
    sm.rb[r][e] = rb > 0.f ? rb : 0.f;
  }
  __syncthreads();
  if (tid < 16) {
    int r = tid;
    float y = 0.f;
#pragma unroll
    for (int e = 0; e < 32; ++e) y = fmaf(sm.hid[r][e], sm.w2[r][e], y);
    float b2v = LD<F32>(b2l2b, 0);
#pragma unroll
    for (int e = 0; e < 32; ++e) b2v = fmaf(sm.rb[r][e], LD<F32>(b2l2W, e), b2v);
    float yv = y + b2v;
    if (F32) ((float*)out)[n0 + r] = yv;
    else ((bf16*)out)[n0 + r] = __float2bfloat16(yv);
  }
}

__global__ __launch_bounds__(256) void causal_mixer_fb(
    const void* qvals, const int* crel, const void* states,
    const void* w00l1W, const void* w00l1b, const void* w00l2W, const void* w00l2b,
    const void* b00W, const void* b00b,
    const void* w01W, const void* w01b, const void* b01W, const void* b01b,
    const void* w1l1W, const void* w1l1b, const void* w1l2W, const void* w1l2b,
    const void* b1W, const void* b1b,
    const void* w2l1W, const void* w2l1b, const void* w2l2W, const void* w2l2b,
    const void* b2l1W, const void* b2l1b, const void* b2l2W, const void* b2l2b,
    void* out) {
  __shared__ SmemF sm;
  const int tid = threadIdx.x;
  const int n0 = blockIdx.x * 16;
  const int b_blk = n0 >> 6;
  if (detect_f32(states))
    fb_body<true>(sm, tid, n0, b_blk, qvals, crel, states, w00l1W, w00l1b, w00l2W, w00l2b,
        b00W, b00b, w01W, w01b, b01W, b01b, w1l1W, w1l1b, w1l2W, w1l2b, b1W, b1b,
        w2l1W, w2l1b, w2l2W, w2l2b, b2l1W, b2l1b, b2l2W, b2l2b, out);
  else
    fb_body<false>(sm, tid, n0, b_blk, qvals, crel, states, w00l1W, w00l1b, w00l2W, w00l2b,
        b00W, b00b, w01W, w01b, b01W, b01b, w1l1W, w1l1b, w1l2W, w1l2b, b1W, b1b,
        w2l1W, w2l1b, w2l2W, w2l2b, b2l1W, b2l1b, b2l2W, b2l2b, out);
}

extern "C" void kernel_launch(void* const* d_in, const int* in_sizes, int n_in,
                              void* d_out, int out_size, void* d_ws, size_t ws_size,
                              hipStream_t stream) {
  char* ws = (char*)d_ws;
  if (ws_size >= WS_NEED) {
    hipLaunchKernelGGL(prep_kernel, dim3(256), dim3(256), 0, stream, ws, d_in[2],
        d_in[3], d_in[4], d_in[5], d_in[6], d_in[7], d_in[8],
        d_in[9], d_in[10], d_in[11], d_in[12],
        d_in[13], d_in[14], d_in[15], d_in[16], d_in[17], d_in[18],
        d_in[19], d_in[20], d_in[21], d_in[22], d_in[23], d_in[24],
        d_in[25], d_in[26]);
    hipLaunchKernelGGL(causal_mixer_mfma, dim3(256), dim3(512), 0, stream, ws,
        d_in[0], (const int*)d_in[1], d_in[2], d_out);
  } else {
    hipLaunchKernelGGL(causal_mixer_fb, dim3(512), dim3(256), 0, stream,
        d_in[0], (const int*)d_in[1], d_in[2],
        d_in[3], d_in[4], d_in[5], d_in[6], d_in[7], d_in[8],
        d_in[9], d_in[10], d_in[11], d_in[12],
        d_in[13], d_in[14], d_in[15], d_in[16], d_in[17], d_in[18],
        d_in[19], d_in[20], d_in[21], d_in[22], d_in[23], d_in[24],
        d_in[25], d_in[26],
        d_out);
  }
}

// Round 10
// 169.965 us; speedup vs baseline: 1.0033x; 1.0033x over previous
//
#include <hip/hip_runtime.h>
#include <hip/hip_bf16.h>

// CausalMixer: B=128, T=64, NA=10, NV=16, K=4, SD=512, H=256, E=32. 8192 rows.
// Round 10: load-depth attack. Staging issues all 8 16-B loads/thread before
// converting (HBM depth ~64KB/CU in flight); phase-A/B initial B-tile loads
// issued before their barriers. ks-outer MFMA loops from R9 unchanged.

typedef __hip_bfloat16 bf16;
typedef unsigned short ushort_t;
typedef __attribute__((ext_vector_type(8))) short short8;
typedef __attribute__((ext_vector_type(4))) float f32x4;

#define PA_OFF 0
#define PA_TILES 56                                  // N=896 padded (844 real)
#define PB_OFF (PA_TILES * 16 * 64 * 8 * 2)          // 917504
#define PB_TILES 36                                  // N=576 exact
#define FB_OFF (PB_OFF + PB_TILES * 8 * 64 * 8 * 2)  // 1212416
#define NCST 2854
#define WS_NEED (size_t)(FB_OFF + NCST * 4 + 32)

#define MFMA16(a, b, c) __builtin_amdgcn_mfma_f32_16x16x32_bf16(a, b, c, 0, 0, 0)

__device__ __forceinline__ float us2f(ushort_t x) {
  unsigned u = ((unsigned)x) << 16; float f; __builtin_memcpy(&f, &u, 4); return f;
}
__device__ __forceinline__ ushort_t f2us(float v) {
  bf16 h = __float2bfloat16(v); ushort_t r; __builtin_memcpy(&r, &h, 2); return r;
}
template <bool F32>
__device__ __forceinline__ float LD(const void* p, size_t i) {
  if (F32) return ((const float*)p)[i];
  return us2f(((const ushort_t*)p)[i]);
}

// wave-level dtype probe: 1 = float32, 0 = bf16
__device__ __forceinline__ int detect_f32(const void* states) {
  const unsigned short* u = (const unsigned short*)states;
  int lane = threadIdx.x & 63;
  int bad = 0;
  for (int i = lane; i < 512; i += 64) {
    unsigned short x = u[i];
    int e = (x >> 7) & 0xFF;
    if (e > 140 || (((x & 0x7FFFu) != 0) && e < 100)) bad++;
  }
  for (int off = 32; off; off >>= 1) bad += __shfl_down(bad, off);
  return __shfl(bad, 0) > 20;
}

// packed-layout stores: element (n', k) -> MFMA lane order
__device__ __forceinline__ void pa_store(ushort_t* pa, int np, int k, ushort_t v) {
  int t = np >> 4, lm = np & 15, ks = k >> 5, qq = (k >> 3) & 3, j = k & 7;
  pa[(size_t)t * 8192 + ks * 512 + (qq * 16 + lm) * 8 + j] = v;
}
__device__ __forceinline__ void pb_store(ushort_t* pb, int np, int k, ushort_t v) {
  int t = np >> 4, lm = np & 15, ks = k >> 5, qq = (k >> 3) & 3, j = k & 7;
  pb[(size_t)t * 4096 + ks * 512 + (qq * 16 + lm) * 8 + j] = v;
}

// ---------------- prep: source-major coalesced reads, scattered u16 writes ----
template <bool F32>
__device__ void prep_body(int gtid, int T, char* ws,
    const void* w00l1W, const void* w00l1b, const void* w00l2W, const void* w00l2b,
    const void* b00W, const void* b00b,
    const void* w01W, const void* w01b, const void* b01W, const void* b01b,
    const void* w1l1W, const void* w1l1b, const void* w1l2W, const void* w1l2b,
    const void* b1W, const void* b1b,
    const void* w2l1W, const void* w2l1b, const void* w2l2W, const void* w2l2b,
    const void* b2l1W, const void* b2l1b, const void* b2l2W, const void* b2l2b) {
  ushort_t* pa = (ushort_t*)(ws + PA_OFF);
  ushort_t* pb = (ushort_t*)(ws + PB_OFF);
  float* cst = (float*)(ws + FB_OFF);
  for (int i = gtid; i < 131072; i += T) {
    int k = i >> 8, n = i & 255;
    pa_store(pa, n, k, f2us(LD<F32>(w1l1W, i)));
    pa_store(pa, 256 + n, k, f2us(LD<F32>(w2l1W, i)));
    pa_store(pa, 512 + n, k, f2us(LD<F32>(w00l1W, i)));
  }
  for (int i = gtid; i < 16384; i += T) {
    int k = i >> 5, n = i & 31;
    pa_store(pa, 768 + n, k, f2us(LD<F32>(b1W, i)));
    pa_store(pa, 800 + n, k, f2us(LD<F32>(b2l1W, i)));
  }
  for (int i = gtid; i < 5120; i += T) {
    int k = i / 10, n = i % 10;
    pa_store(pa, 832 + n, k, f2us(LD<F32>(w01W, i)));
  }
  for (int i = gtid; i < 512; i += T) {
    pa_store(pa, 842, i, f2us(LD<F32>(b00W, i)));
    pa_store(pa, 843, i, f2us(LD<F32>(b01W, i)));
  }
  for (int z = gtid; z < 2048; z += T) {
    int ks = z >> 7, qq = (z >> 5) & 3, lm = 12 + ((z >> 3) & 3), j = z & 7;
    pa[(size_t)52 * 8192 + ks * 512 + (qq * 16 + lm) * 8 + j] = 0;
  }
  for (int i = gtid; i < 139264; i += T) {
    int k = i / 544, n = i % 544;
    pb_store(pb, n, k, f2us(LD<F32>(w1l2W, i)));
  }
  for (int i = gtid; i < 8192; i += T) {
    int k = i >> 5, n = i & 31;
    pb_store(pb, 544 + n, k, f2us(LD<F32>(w2l2W, i)));
  }
  // consts: biasA[0,896) biasB[896,1536) hd[1536,1792) w00l2W[1792,2816)
  //         w00l2b[2816,2820) b2l2W[2820,2852) b2l2b[2852] gd[2853]
  for (int i = gtid; i < NCST; i += T) {
    float x;
    if (i < 896) {
      int c = i;
      if (c < 256) x = LD<F32>(w1l1b, c);
      else if (c < 512) x = LD<F32>(w2l1b, c - 256);
      else if (c < 768) x = LD<F32>(w00l1b, c - 512);
      else if (c < 800) x = LD<F32>(b1b, c - 768);
      else if (c < 832) x = LD<F32>(b2l1b, c - 800);
      else if (c < 842) x = LD<F32>(w01b, c - 832);
      else if (c == 842) x = LD<F32>(b00b, 0);
      else if (c == 843) x = LD<F32>(b01b, 0);
      else x = 0.f;
    } else if (i < 1536) {
      int c = i - 896;
      x = (c < 544) ? LD<F32>(w1l2b, c) : (c < 576 ? LD<F32>(w2l2b, c - 544) : 0.f);
    } else if (i < 1792) {
      int j = i - 1536; float s = 0.f;
      for (int z = 0; z < 16; ++z) s += LD<F32>(w00l1W, (size_t)(512 + z) * 256 + j);
      x = s;
    } else if (i < 2816) x = LD<F32>(w00l2W, i - 1792);
    else if (i < 2820) x = LD<F32>(w00l2b, i - 2816);
    else if (i < 2852) x = LD<F32>(b2l2W, i - 2820);
    else if (i == 2852) x = LD<F32>(b2l2b, 0);
    else { float s = 0.f; for (int z = 0; z < 16; ++z) s += LD<F32>(b00W, 512 + z); x = s; }
    cst[i] = x;
  }
}

__global__ __launch_bounds__(256) void prep_kernel(char* ws, const void* states,
    const void* w00l1W, const void* w00l1b, const void* w00l2W, const void* w00l2b,
    const void* b00W, const void* b00b,
    const void* w01W, const void* w01b, const void* b01W, const void* b01b,
    const void* w1l1W, const void* w1l1b, const void* w1l2W, const void* w1l2b,
    const void* b1W, const void* b1b,
    const void* w2l1W, const void* w2l1b, const void* w2l2W, const void* w2l2b,
    const void* b2l1W, const void* b2l1b, const void* b2l2W, const void* b2l2b) {
  int gtid = blockIdx.x * 256 + threadIdx.x;
  int T = gridDim.x * 256;
  if (detect_f32(states))
    prep_body<true>(gtid, T, ws, w00l1W, w00l1b, w00l2W, w00l2b, b00W, b00b,
        w01W, w01b, b01W, b01b, w1l1W, w1l1b, w1l2W, w1l2b, b1W, b1b,
        w2l1W, w2l1b, w2l2W, w2l2b, b2l1W, b2l1b, b2l2W, b2l2b);
  else
    prep_body<false>(gtid, T, ws, w00l1W, w00l1b, w00l2W, w00l2b, b00W, b00b,
        w01W, w01b, b01W, b01b, w1l1W, w1l1b, w1l2W, w1l2b, b1W, b1b,
        w2l1W, w2l1b, w2l2W, w2l2b, b2l1W, b2l1b, b2l2W, b2l2b);
}

// ---------------- main MFMA kernel: 32 rows/block, 8 waves ----------------
struct SmemM {
  union {
    __align__(16) ushort_t sA[2][8192];   // states, MFMA lane order (phase A only)
    __align__(16) ushort_t w1a[32][544];  // |w1 raw| bf16 (phase B output)
  } u;
  __align__(16) ushort_t Am1[2][4096];    // relu(s@w1l1+b), lane order
  __align__(16) ushort_t Am2[2][4096];    // relu(s@w2l1+b), lane order
  __align__(16) ushort_t hb[32][264];     // s@w00l1+b (pre-relu), linear
  float hd[256];
  float w2l[1024];                        // w00l2W staged
  float b1v[32][32];
  float rbv[32][32];
  float w2v[32][32];
  float w01v[32][12];
  float qv[32][10];
  unsigned char cr[32][64];
  float w0c[32][4], w0s[32][4];
  float gq[32][18];
  float gbv[32], b01v[32];
  float hid[32][33];
};

template <bool F32>
__device__ void mixer_body(SmemM& sm, const char* ws, int n0,
    const void* qvals, const int* crel, const void* states, void* out) {
  const int tid = threadIdx.x;                // 0..511
  const int lane = tid & 63, wv = tid >> 6;   // 8 waves
  const int q = lane >> 4, lm = lane & 15;
  const int b_blk = n0 >> 6;
  const ushort_t* pa = (const ushort_t*)(ws + PA_OFF);
  const ushort_t* pb = (const ushort_t*)(ws + PB_OFF);
  const float* cstg = (const float*)(ws + FB_OFF);

  // phase-A strip assignment (needed early for B prefetch)
  int sidx[7]; bool sreal[7];
#pragma unroll
  for (int i = 0; i < 7; ++i) {
    int s = wv + 8 * i;
    sreal[i] = (s < 53);
    sidx[i] = sreal[i] ? s : wv;
  }
  const ushort_t* baseA = pa + lane * 8;

  // ---- stage: batched deep loads (all loads issued before any use) ----
  short8 curA[7];
  if (F32) {
    f32x4 va[8];
#pragma unroll
    for (int it = 0; it < 4; ++it) {
      int fi = tid + it * 512;
      int ln = fi & 63, ks = (fi >> 6) & 15, G = fi >> 10;
      int row = G * 16 + (ln & 15), col = ks * 32 + (ln >> 4) * 8;
      const f32x4* p = (const f32x4*)((const float*)states + (size_t)(n0 + row) * 512 + col);
      va[2 * it] = p[0];
      va[2 * it + 1] = p[1];
    }
    // early phase-A B-tile loads (L2) — overlap with staging latency
#pragma unroll
    for (int i = 0; i < 7; ++i) curA[i] = *(const short8*)(baseA + (size_t)sidx[i] * 8192);
#pragma unroll
    for (int it = 0; it < 4; ++it) {
      int fi = tid + it * 512;
      int ln = fi & 63, ks = (fi >> 6) & 15, G = fi >> 10;
      f32x4 v0 = va[2 * it], v1 = va[2 * it + 1];
      ushort_t v[8];
      v[0] = f2us(v0[0]); v[1] = f2us(v0[1]); v[2] = f2us(v0[2]); v[3] = f2us(v0[3]);
      v[4] = f2us(v1[0]); v[5] = f2us(v1[1]); v[6] = f2us(v1[2]); v[7] = f2us(v1[3]);
      *(short8*)&sm.u.sA[G][(size_t)(ks * 64 + ln) * 8] = *(short8*)v;
    }
  } else {
    short8 vb[2];
#pragma unroll
    for (int it = 0; it < 2; ++it) {
      int fi = tid + it * 512;
      int ln = fi & 63, ks = (fi >> 6) & 15, G = fi >> 10;
      int row = G * 16 + (ln & 15), col = ks * 32 + (ln >> 4) * 8;
      vb[it] = *(const short8*)((const ushort_t*)states + (size_t)(n0 + row) * 512 + col);
    }
#pragma unroll
    for (int i = 0; i < 7; ++i) curA[i] = *(const short8*)(baseA + (size_t)sidx[i] * 8192);
#pragma unroll
    for (int it = 0; it < 2; ++it) {
      int fi = tid + it * 512;
      int ln = fi & 63, ks = (fi >> 6) & 15, G = fi >> 10;
      *(short8*)&sm.u.sA[G][(size_t)(ks * 64 + ln) * 8] = vb[it];
    }
  }
  for (int i = tid; i < 320; i += 512) sm.qv[i / 10][i % 10] = LD<F32>(qvals, (size_t)(n0 + i / 10) * 10 + i % 10);
  for (int i = tid; i < 2048; i += 512) sm.cr[i >> 6][i & 63] = (unsigned char)crel[(size_t)n0 * 64 + i];
  if (tid < 256) sm.hd[tid] = cstg[1536 + tid];
  for (int i = tid; i < 1024; i += 512) sm.w2l[i] = cstg[1792 + i];
  __syncthreads();

  // ---- Phase A: ks-outer, 7 strips/wave inner. acc live across K. ----
  {
    f32x4 accA[7][2];
#pragma unroll
    for (int i = 0; i < 7; ++i) { accA[i][0] = (f32x4){0,0,0,0}; accA[i][1] = (f32x4){0,0,0,0}; }
    short8 nxt[7];
#pragma unroll
    for (int ks = 0; ks < 16; ++ks) {
      if (ks < 15) {
#pragma unroll
        for (int i = 0; i < 7; ++i)
          nxt[i] = *(const short8*)(baseA + (size_t)sidx[i] * 8192 + (ks + 1) * 512);
      }
      short8 a0 = *(const short8*)&sm.u.sA[0][(ks * 64 + lane) * 8];
      short8 a1 = *(const short8*)&sm.u.sA[1][(ks * 64 + lane) * 8];
#pragma unroll
      for (int i = 0; i < 7; ++i) {
        accA[i][0] = MFMA16(a0, curA[i], accA[i][0]);
        accA[i][1] = MFMA16(a1, curA[i], accA[i][1]);
      }
#pragma unroll
      for (int i = 0; i < 7; ++i) curA[i] = nxt[i];
    }
    // writeback
#pragma unroll
    for (int i = 0; i < 7; ++i) {
      if (!sreal[i]) continue;
      int c = sidx[i] * 16 + lm;
      if (c >= 844) continue;
      float bias = cstg[c];
      int ks2 = (c & 255) >> 5, q2 = (c >> 3) & 3, j2 = c & 7;
#pragma unroll
      for (int G = 0; G < 2; ++G) {
        f32x4 acc = accA[i][G];
        int rb = G * 16 + q * 4;
        if (c < 256) {
#pragma unroll
          for (int g = 0; g < 4; ++g) {
            float v = acc[g] + bias;
            sm.Am1[G][(ks2 * 64 + q2 * 16 + q * 4 + g) * 8 + j2] = f2us(v > 0.f ? v : 0.f);
          }
        } else if (c < 512) {
#pragma unroll
          for (int g = 0; g < 4; ++g) {
            float v = acc[g] + bias;
            sm.Am2[G][(ks2 * 64 + q2 * 16 + q * 4 + g) * 8 + j2] = f2us(v > 0.f ? v : 0.f);
          }
        } else if (c < 768) {
#pragma unroll
          for (int g = 0; g < 4; ++g) sm.hb[rb + g][c - 512] = f2us(acc[g] + bias);
        } else if (c < 800) {
#pragma unroll
          for (int g = 0; g < 4; ++g) sm.b1v[rb + g][c - 768] = acc[g] + bias;
        } else if (c < 832) {
#pragma unroll
          for (int g = 0; g < 4; ++g) { float v = acc[g] + bias; sm.rbv[rb + g][c - 800] = v > 0.f ? v : 0.f; }
        } else if (c < 842) {
#pragma unroll
          for (int g = 0; g < 4; ++g) sm.w01v[rb + g][c - 832] = acc[g] + bias;
        } else if (c == 842) {
#pragma unroll
          for (int g = 0; g < 4; ++g) sm.gbv[rb + g] = acc[g] + bias;
        } else {
#pragma unroll
          for (int g = 0; g < 4; ++g) sm.b01v[rb + g] = acc[g] + bias;
        }
      }
    }
  }

  // phase-B strip assignment + early B-tile loads (before the barrier)
  int tix[5]; bool treal[5];
#pragma unroll
  for (int i = 0; i < 5; ++i) {
    int t = wv + 8 * i;
    treal[i] = (t < 36);
    tix[i] = treal[i] ? t : wv;
  }
  const ushort_t* baseB = pb + lane * 8;
  short8 curB[5];
#pragma unroll
  for (int i = 0; i < 5; ++i) curB[i] = *(const short8*)(baseB + (size_t)tix[i] * 4096);
  __syncthreads();

  // ---- Phase B: ks-outer, 5 strips/wave. strips 0..33 from Am1, 34..35 Am2 ----
  {
    f32x4 accB[5][2];
#pragma unroll
    for (int i = 0; i < 5; ++i) { accB[i][0] = (f32x4){0,0,0,0}; accB[i][1] = (f32x4){0,0,0,0}; }
    short8 nxt[5];
#pragma unroll
    for (int ks = 0; ks < 8; ++ks) {
      if (ks < 7) {
#pragma unroll
        for (int i = 0; i < 5; ++i)
          nxt[i] = *(const short8*)(baseB + (size_t)tix[i] * 4096 + (ks + 1) * 512);
      }
      short8 m1a0 = *(const short8*)&sm.Am1[0][(ks * 64 + lane) * 8];
      short8 m1a1 = *(const short8*)&sm.Am1[1][(ks * 64 + lane) * 8];
      short8 m2a0 = *(const short8*)&sm.Am2[0][(ks * 64 + lane) * 8];
      short8 m2a1 = *(const short8*)&sm.Am2[1][(ks * 64 + lane) * 8];
#pragma unroll
      for (int i = 0; i < 5; ++i) {
        short8 x0 = (tix[i] < 34) ? m1a0 : m2a0;
        short8 x1 = (tix[i] < 34) ? m1a1 : m2a1;
        accB[i][0] = MFMA16(x0, curB[i], accB[i][0]);
        accB[i][1] = MFMA16(x1, curB[i], accB[i][1]);
      }
#pragma unroll
      for (int i = 0; i < 5; ++i) curB[i] = nxt[i];
    }
#pragma unroll
    for (int i = 0; i < 5; ++i) {
      if (!treal[i]) continue;
      int c = tix[i] * 16 + lm;
      float bias = cstg[896 + c];
#pragma unroll
      for (int G = 0; G < 2; ++G) {
        f32x4 acc = accB[i][G];
        int rb = G * 16 + q * 4;
        if (c < 544) {
#pragma unroll
          for (int g = 0; g < 4; ++g) sm.u.w1a[rb + g][c] = f2us(fabsf(acc[g] + bias));
        } else {
          int e = c - 544;
#pragma unroll
          for (int g = 0; g < 4; ++g) sm.w2v[rb + g][e] = fabsf(acc[g] + bias);
        }
      }
    }
  }
  __syncthreads();

  // ---- C1: w0c/w0s = relu(hb [+hd]) @ w00l2 + b ----
  if (tid < 256) {
    int r = tid >> 3, k = (tid >> 1) & 3, sflag = tid & 1;
    float a = 0.f;
    for (int j = 0; j < 256; ++j) {
      float h = us2f(sm.hb[r][j]);
      if (sflag) h += sm.hd[j];
      h = h > 0.f ? h : 0.f;
      a = fmaf(h, sm.w2l[j * 4 + k], a);
    }
    a += cstg[2816 + k];
    if (sflag) sm.w0s[r][k] = a; else sm.w0c[r][k] = a;
  }
  __syncthreads();

  // ---- C2: gq ----
  {
    int r = tid >> 4, v = tid & 15;
    bool sp = (v == b_blk);
    const float* w0 = sp ? sm.w0s[r] : sm.w0c[r];
    float g = sm.gbv[r] + (sp ? cstg[2853] : 0.f);
#pragma unroll
    for (int k = 0; k < 4; ++k) {
      int a = sm.cr[r][k * 16 + v];
      g = fmaf(sm.qv[r][a], fabsf(w0[k]), g);
    }
    sm.gq[r][v] = g;
  }
  if (tid < 32) {
    float o = sm.b01v[tid];
#pragma unroll
    for (int a = 0; a < 10; ++a) o = fmaf(sm.qv[tid][a], sm.w01v[tid][a], o);
    sm.gq[tid][16] = o;
  }
  __syncthreads();

  // ---- C3: hidden = elu(sum_v gq*|w1| + b1); fuse *w2 + rb*b2l2W ----
  for (int p = tid; p < 1024; p += 512) {
    int r = p >> 5, e = p & 31;
    float h = sm.b1v[r][e];
#pragma unroll
    for (int v = 0; v < 17; ++v) h = fmaf(sm.gq[r][v], us2f(sm.u.w1a[r][v * 32 + e]), h);
    float hid = h > 0.f ? h : (expf(h) - 1.f);
    sm.hid[r][e] = hid * sm.w2v[r][e] + sm.rbv[r][e] * cstg[2820 + e];
  }
  __syncthreads();

  // ---- C4: reduce + store ----
  if (tid < 32) {
    float y = cstg[2852];
#pragma unroll
    for (int e = 0; e < 32; ++e) y += sm.hid[tid][e];
    if (F32) ((float*)out)[n0 + tid] = y;
    else ((bf16*)out)[n0 + tid] = __float2bfloat16(y);
  }
}

__global__ __launch_bounds__(512, 2) void causal_mixer_mfma(const char* ws,
    const void* qvals, const int* crel, const void* states, void* out) {
  __shared__ SmemM sm;
  int n0 = blockIdx.x * 32;
  if (detect_f32(states))
    mixer_body<true>(sm, ws, n0, qvals, crel, states, out);
  else
    mixer_body<false>(sm, ws, n0, qvals, crel, states, out);
}

// ---------------- fallback scalar kernel (round-2, proven) ----------------
struct SmemF {
  float s[16][516]; float buf[16][258]; float hd[256];
  float q[16][10]; int cr[16][66];
  float w0c[16][4], w0s[16][4]; float gq[16][17];
  float w01[16][10]; float b01[16]; float gb[16]; float gd;
  float hid[16][32]; float w2[16][32]; float rb[16][32];
};

template <bool F32>
__device__ void fb_body(SmemF& sm, int tid, int n0, int b_blk,
    const void* qvals, const int* crel, const void* states,
    const void* w00l1W, const void* w00l1b, const void* w00l2W, const void* w00l2b,
    const void* b00W, const void* b00b,
    const void* w01W, const void* w01b, const void* b01W, const void* b01b,
    const void* w1l1W, const void* w1l1b, const void* w1l2W, const void* w1l2b,
    const void* b1W, const void* b1b,
    const void* w2l1W, const void* w2l1b, const void* w2l2W, const void* w2l2b,
    const void* b2l1W, const void* b2l1b, const void* b2l2W, const void* b2l2b,
    void* out) {
  for (int idx = tid; idx < 16 * 512; idx += 256) {
    int r = idx >> 9, i = idx & 511;
    sm.s[r][i] = LD<F32>(states, (size_t)(n0 + r) * 512 + i);
  }
  for (int idx = tid; idx < 160; idx += 256) {
    int r = idx / 10, a = idx % 10;
    sm.q[r][a] = LD<F32>(qvals, (size_t)(n0 + r) * 10 + a);
  }
  for (int idx = tid; idx < 16 * 64; idx += 256) {
    int r = idx >> 6, kv = idx & 63;
    sm.cr[r][kv] = crel[(size_t)(n0 + r) * 64 + kv];
  }
  if (tid == 0) {
    float gd = 0.f;
    for (int i = 512; i < 528; ++i) gd += LD<F32>(b00W, i);
    sm.gd = gd;
  }
  __syncthreads();
  {
    const int j = tid;
    float hd = 0.f;
    for (int i = 0; i < 16; ++i) hd += LD<F32>(w00l1W, (size_t)(512 + i) * 256 + j);
    sm.hd[j] = hd;
    float acc[16]; float bj = LD<F32>(w00l1b, j);
#pragma unroll
    for (int r = 0; r < 16; ++r) acc[r] = bj;
    for (int i = 0; i < 512; ++i) {
      float w = LD<F32>(w00l1W, (size_t)i * 256 + j);
#pragma unroll
      for (int r = 0; r < 16; ++r) acc[r] = fmaf(sm.s[r][i], w, acc[r]);
    }
#pragma unroll
    for (int r = 0; r < 16; ++r) sm.buf[r][j] = acc[r];
  }
  __syncthreads();
  if (tid < 64) {
    int r = tid >> 2, k = tid & 3;
    float aC = 0.f, aS = 0.f;
    for (int j = 0; j < 256; ++j) {
      float hb = sm.buf[r][j];
      float w = LD<F32>(w00l2W, j * 4 + k);
      float hc = hb > 0.f ? hb : 0.f;
      float hbs = hb + sm.hd[j];
      float hsv = hbs > 0.f ? hbs : 0.f;
      aC = fmaf(hc, w, aC); aS = fmaf(hsv, w, aS);
    }
    float bk = LD<F32>(w00l2b, k);
    sm.w0c[r][k] = aC + bk; sm.w0s[r][k] = aS + bk;
  } else if (tid < 224) {
    int p = tid - 64; int r = p / 10, a = p % 10;
    float acc = 0.f;
    for (int i = 0; i < 512; ++i) acc = fmaf(sm.s[r][i], LD<F32>(w01W, (size_t)i * 10 + a), acc);
    sm.w01[r][a] = acc + LD<F32>(w01b, a);
  } else if (tid < 240) {
    int r = tid - 224;
    float acc = 0.f;
    for (int i = 0; i < 512; ++i) acc = fmaf(sm.s[r][i], LD<F32>(b00W, i), acc);
    sm.gb[r] = acc + LD<F32>(b00b, 0);
  } else {
    int r = tid - 240;
    float acc = 0.f;
    for (int i = 0; i < 512; ++i) acc = fmaf(sm.s[r][i], LD<F32>(b01W, i), acc);
    sm.b01[r] = acc + LD<F32>(b01b, 0);
  }
  __syncthreads();
  {
    int r = tid >> 4, v = tid & 15;
    bool sp = (v == b_blk);
    const float* w0 = sp ? sm.w0s[r] : sm.w0c[r];
    float g = sm.gb[r] + (sp ? sm.gd : 0.f);
#pragma unroll
    for (int k = 0; k < 4; ++k) {
      int a = sm.cr[r][k * 16 + v];
      g = fmaf(sm.q[r][a], fabsf(w0[k]), g);
    }
    sm.gq[r][v] = g;
  }
  if (tid < 16) {
    int r = tid;
    float o = sm.b01[r];
    for (int a = 0; a < 10; ++a) o = fmaf(sm.q[r][a], sm.w01[r][a], o);
    sm.gq[r][16] = o;
  }
  __syncthreads();
  {
    const int j = tid;
    float acc[16]; float bj = LD<F32>(w1l1b, j);
#pragma unroll
    for (int r = 0; r < 16; ++r) acc[r] = bj;
    for (int i = 0; i < 512; ++i) {
      float w = LD<F32>(w1l1W, (size_t)i * 256 + j);
#pragma unroll
      for (int r = 0; r < 16; ++r) acc[r] = fmaf(sm.s[r][i], w, acc[r]);
    }
#pragma unroll
    for (int r = 0; r < 16; ++r) sm.buf[r][j] = acc[r] > 0.f ? acc[r] : 0.f;
  }
  __syncthreads();
  for (int p = tid; p < 512; p += 256) {
    int r = p >> 5, e = p & 31;
    float acc = 0.f;
    for (int v = 0; v < 17; ++v) {
      int c = v * 32 + e;
      float d = LD<F32>(w1l2b, c);
      for (int j = 0; j < 256; ++j) d = fmaf(sm.buf[r][j], LD<F32>(w1l2W, (size_t)j * 544 + c), d);
      acc = fmaf(sm.gq[r][v], fabsf(d), acc);
    }
    float b1v = LD<F32>(b1b, e);
    for (int i = 0; i < 512; ++i) b1v = fmaf(sm.s[r][i], LD<F32>(b1W, (size_t)i * 32 + e), b1v);
    float x = acc + b1v;
    sm.hid[r][e] = x > 0.f ? x : (expf(x) - 1.f);
  }
  __syncthreads();
  {
    const int j = tid;
    float acc[16]; float bj = LD<F32>(w2l1b, j);
#pragma unroll
    for (int r = 0; r < 16; ++r) acc[r] = bj;
    for (int i = 0; i < 512; ++i) {
      float w = LD<F32>(w2l1W, (size_t)i * 256 + j);
#pragma unroll
      for (int r = 0; r < 16; ++r) acc[r] = fmaf(sm.s[r][i], w, acc[r]);
    }
#pragma unroll
    for (int r = 0; r < 16; ++r) sm.buf[r][j] = acc[r] > 0.f ? acc[r] : 0.f;
  }
  __syncthreads();
  for (int p = tid; p < 512; p += 256) {
    int r = p >> 5, e = p & 31;
    float d = LD<F32>(w2l2b, e);
    for (int j = 0; j < 256; ++j) d = fmaf(sm.buf[r][j], LD<F32>(w2l2W, (size_t)j * 32 + e), d);
    sm.w2[r][e] = fabsf(d);
    float rb = LD<F32>(b2l1b, e);
    for (int i = 0; i < 512; ++i) rb = fmaf(sm.s[r][i], LD<F32>(b2l1W, (size_t)i * 32 + e), rb);
    sm.rb[r][e] = rb > 0.f ? rb : 0.f;
  }
  __syncthreads();
  if (tid < 16) {
    int r = tid;
    float y = 0.f;
#pragma unroll
    for (int e = 0; e < 32; ++e) y = fmaf(sm.hid[r][e], sm.w2[r][e], y);
    float b2v = LD<F32>(b2l2b, 0);
#pragma unroll
    for (int e = 0; e < 32; ++e) b2v = fmaf(sm.rb[r][e], LD<F32>(b2l2W, e), b2v);
    float yv = y + b2v;
    if (F32) ((float*)out)[n0 + r] = yv;
    else ((bf16*)out)[n0 + r] = __float2bfloat16(yv);
  }
}

__global__ __launch_bounds__(256) void causal_mixer_fb(
    const void* qvals, const int* crel, const void* states,
    const void* w00l1W, const void* w00l1b, const void* w00l2W, const void* w00l2b,
    const void* b00W, const void* b00b,
    const void* w01W, const void* w01b, const void* b01W, const void* b01b,
    const void* w1l1W, const void* w1l1b, const void* w1l2W, const void* w1l2b,
    const void* b1W, const void* b1b,
    const void* w2l1W, const void* w2l1b, const void* w2l2W, const void* w2l2b,
    const void* b2l1W, const void* b2l1b, const void* b2l2W, const void* b2l2b,
    void* out) {
  __shared__ SmemF sm;
  const int tid = threadIdx.x;
  const int n0 = blockIdx.x * 16;
  const int b_blk = n0 >> 6;
  if (detect_f32(states))
    fb_body<true>(sm, tid, n0, b_blk, qvals, crel, states, w00l1W, w00l1b, w00l2W, w00l2b,
        b00W, b00b, w01W, w01b, b01W, b01b, w1l1W, w1l1b, w1l2W, w1l2b, b1W, b1b,
        w2l1W, w2l1b, w2l2W, w2l2b, b2l1W, b2l1b, b2l2W, b2l2b, out);
  else
    fb_body<false>(sm, tid, n0, b_blk, qvals, crel, states, w00l1W, w00l1b, w00l2W, w00l2b,
        b00W, b00b, w01W, w01b, b01W, b01b, w1l1W, w1l1b, w1l2W, w1l2b, b1W, b1b,
        w2l1W, w2l1b, w2l2W, w2l2b, b2l1W, b2l1b, b2l2W, b2l2b, out);
}

extern "C" void kernel_launch(void* const* d_in, const int* in_sizes, int n_in,
                              void* d_out, int out_size, void* d_ws, size_t ws_size,
                              hipStream_t stream) {
  char* ws = (char*)d_ws;
  if (ws_size >= WS_NEED) {
    hipLaunchKernelGGL(prep_kernel, dim3(256), dim3(256), 0, stream, ws, d_in[2],
        d_in[3], d_in[4], d_in[5], d_in[6], d_in[7], d_in[8],
        d_in[9], d_in[10], d_in[11], d_in[12],
        d_in[13], d_in[14], d_in[15], d_in[16], d_in[17], d_in[18],
        d_in[19], d_in[20], d_in[21], d_in[22], d_in[23], d_in[24],
        d_in[25], d_in[26]);
    hipLaunchKernelGGL(causal_mixer_mfma, dim3(256), dim3(512), 0, stream, ws,
        d_in[0], (const int*)d_in[1], d_in[2], d_out);
  } else {
    hipLaunchKernelGGL(causal_mixer_fb, dim3(512), dim3(256), 0, stream,
        d_in[0], (const int*)d_in[1], d_in[2],
        d_in[3], d_in[4], d_in[5], d_in[6], d_in[7], d_in[8],
        d_in[9], d_in[10], d_in[11], d_in[12],
        d_in[13], d_in[14], d_in[15], d_in[16], d_in[17], d_in[18],
        d_in[19], d_in[20], d_in[21], d_in[22], d_in[23], d_in[24],
        d_in[25], d_in[26],
        d_out);
  }
}